// Round 10
// baseline (22906.248 us; speedup 1.0000x reference)
//
#include <hip/hip_runtime.h>
#include <stdint.h>

typedef unsigned int u32;
typedef float  f32x4 __attribute__((ext_vector_type(4)));
typedef float  f32x2 __attribute__((ext_vector_type(2)));
typedef double f64x2 __attribute__((ext_vector_type(2)));
typedef double f64x4 __attribute__((ext_vector_type(4)));

constexpr int NT = 256;   // threads per block
constexpr int BB = 256;   // batch
constexpr int ZD = 256;
constexpr int TD = 512;
constexpr int CF = 1024;
constexpr int G4 = 4096;
constexpr int NA = 64;
constexpr int NSTEP = 64;
constexpr int TS_OFF = BB * NSTEP * NA;   // acts [256][64][64] then ts [256][64]

// f64 MFMA GEMM: 64x64 tile, 4 waves of 32x32, k-chunk 32 (round-3 structure).
// HW-VERIFIED (round-2 probe, H2): D(lane=16q+m, reg v) -> row q+4v, col m.
// RSF=35 (280B row stride): round-7 MEASURED zero bank conflicts for this exact
// write (f64x2 at tr*RSF+tkq*8+j*2) and read ((row)*RSF+sp*8+q*2) pattern.
constexpr int RSF = 35;
// dgemm32 stride: 65 = 1 mod 32 -> staging writes 2-way (free), reads broadcast/uniform.
// (68 = 4 mod 32 was a 4-way write conflict = round-3's 7.34M conflict cycles.)
constexpr int FRS = 65;
constexpr int SMEMB = 2 * 64 * RSF * 8;   // 35840 B (mgemm64); dgemm32 needs 33280 B

struct P {
  const float *z, *W_z2t, *b_z2t, *E, *Wih_a, *Whh_a, *bih_a, *bhh_a,
              *Wih_t, *Whh_t, *bih_t, *bhh_t, *W_act, *b_act, *W_ts1, *b_ts1, *W_ts2, *b_ts2;
  float* out;                                               // float32 output (ref dtype)
  // f64 argmax-critical path
  double *t_rec64, *pre_a64, *E_proj_a64, *h_a64, *c_a64, *gacc_a;  // h_a64 dbuf [2][256][1024]
  // f32 ts path
  float *t_rec32, *pre_t, *E_proj_t, *colt, *h_t, *c_t, *gacc_t, *ts_accum;  // h_t dbuf [2][..]
  int* idxb;
};

__device__ __forceinline__ float sigf(float x){ return 1.f / (1.f + expf(-x)); }
__device__ __forceinline__ float tanhf_(float x){
  float ax = fabsf(x); float e = expf(-2.f * ax);
  float t = 1.f - 2.f * e / (1.f + e);
  return x < 0.f ? -t : t;
}
__device__ __forceinline__ double sigd(double x){ return 1.0 / (1.0 + exp(-x)); }

// ---------------- setup: t_rec (f64+f32), state init ----------------
__global__ void __launch_bounds__(NT) k_setup(P p){
  __shared__ double sz[ZD];
  const int bid = blockIdx.x, tid = threadIdx.x;
  for (int i = tid; i < ZD; i += NT) sz[i] = (double)p.z[bid * ZD + i];
  __syncthreads();
  for (int k = tid; k < TD; k += NT){
    const float* wr = p.W_z2t + (size_t)k * ZD;
    double a = 0.0;
    for (int j = 0; j < ZD; ++j) a = fma((double)wr[j], sz[j], a);
    a += (double)p.b_z2t[k];
    double t = a > 0.0 ? a : 0.0;
    p.t_rec64[(size_t)bid * TD + k] = t;
    p.t_rec32[(size_t)bid * TD + k] = (float)t;
  }
  for (int i = tid; i < CF; i += NT){
    p.c_a64[(size_t)bid * CF + i] = 0.0;
    p.h_a64[(size_t)bid * CF + i] = 0.0;  // buffer 0
    p.c_t[(size_t)bid * CF + i] = 0.f;
    p.h_t[(size_t)bid * CF + i] = 0.f;    // buffer 0
  }
  if (tid == 0){ p.idxb[bid] = NA - 1; p.ts_accum[bid] = 0.f; }
}

// ---------------- E_proj tables + colt. grid 528 ----------------
__global__ void __launch_bounds__(NT) k_eproj(P p){
  __shared__ double sz[ZD];
  const int bid = blockIdx.x, tid = threadIdx.x;
  if (bid < 256){            // E_proj_a64: row bid>>2, col chunk bid&3 (1024 cols)
    const int erow = bid >> 2, cchunk = bid & 3;
    for (int i = tid; i < ZD; i += NT) sz[i] = (double)p.E[erow * ZD + i];
    __syncthreads();
    for (int ci = 0; ci < 4; ++ci){
      const int c = cchunk * 1024 + ci * 256 + tid;
      const float* wr = p.Wih_a + (size_t)c * 768 + 512;
      double a = 0.0;
      for (int j = 0; j < 256; ++j) a = fma((double)wr[j], sz[j], a);
      p.E_proj_a64[(size_t)erow * G4 + c] = a;
    }
  } else if (bid < 512){     // E_proj_t (f32)
    const int erow = (bid - 256) >> 2, cchunk = (bid - 256) & 3;
    for (int i = tid; i < ZD; i += NT) sz[i] = (double)p.E[erow * ZD + i];
    __syncthreads();
    for (int ci = 0; ci < 4; ++ci){
      const int c = cchunk * 1024 + ci * 256 + tid;
      const float* wr = p.Wih_t + (size_t)c * 769 + 512;
      float a = 0.f;
      for (int j = 0; j < 256; ++j) a = fmaf(wr[j], (float)sz[j], a);
      p.E_proj_t[(size_t)erow * G4 + c] = a;
    }
  } else {                   // colt
    const int c = (bid - 512) * 256 + tid;
    p.colt[c] = p.Wih_t[(size_t)c * 769 + 768];
  }
}

// ---------------- f64 MFMA GEMM: 64x64 tile. HW-verified core (round-2 probe, H2) ----------------
// A f64 (A64) or f32 rows (lda), B f32 rows (ldb), K mult of 32. Per-row LDS k-permutation:
// write pair (k, k+4) to adjacent f64 slots; read at sp*8+q*2 gives the (k=8sp+q, k=8sp+q+4)
// MFMA pair for lane quadrant q.
template <bool A64, bool OUT64, bool BIAS>
__device__ void mgemm64(char* smem, const void* __restrict__ Av, int lda,
                        const float* __restrict__ B, int ldb,
                        int rowb, int colb, int K,
                        const void* __restrict__ addin,
                        const float* __restrict__ bih, const float* __restrict__ bhh,
                        void* __restrict__ outv){
  double* As = (double*)smem;
  double* Bs = As + 64 * RSF;
  const int tid = threadIdx.x;
  const int lane = tid & 63;
  const int wm = (tid >> 7) & 1, wn = (tid >> 6) & 1;   // wave -> 2x2 grid of 32x32 tiles
  const int m = lane & 15, q = lane >> 4;
  const int tr = tid >> 2, tkq = tid & 3;               // staging: row/col tr, k-octet tkq
  const double* A64p = (const double*)Av;
  const float*  A32p = (const float*)Av;

  double av[8], bv[8];
  auto loadchunk = [&](int kb){
    if (A64){
      const double* ap = A64p + (size_t)(rowb + tr) * lda + kb + tkq * 8;
      #pragma unroll
      for (int j = 0; j < 8; ++j) av[j] = ap[j];
    } else {
      const float* ap = A32p + (size_t)(rowb + tr) * lda + kb + tkq * 8;
      #pragma unroll
      for (int j = 0; j < 8; ++j) av[j] = (double)ap[j];
    }
    const float* bp = B + (size_t)(colb + tr) * ldb + kb + tkq * 8;
    #pragma unroll
    for (int j = 0; j < 8; ++j) bv[j] = (double)bp[j];
  };
  f64x4 acc[2][2];
  #pragma unroll
  for (int g = 0; g < 2; ++g)
    #pragma unroll
    for (int h = 0; h < 2; ++h) acc[g][h] = f64x4{0.0,0.0,0.0,0.0};

  loadchunk(0);
  for (int kb = 0; kb < K; kb += 32){
    __syncthreads();
    {
      double* arow = As + tr * RSF + tkq * 8;
      double* brow = Bs + tr * RSF + tkq * 8;
      #pragma unroll
      for (int j = 0; j < 4; ++j){                // pair (k, k+4) -> adjacent slots
        *(f64x2*)(arow + j * 2) = f64x2{av[j], av[j + 4]};
        *(f64x2*)(brow + j * 2) = f64x2{bv[j], bv[j + 4]};
      }
    }
    __syncthreads();
    if (kb + 32 < K) loadchunk(kb + 32);          // register prefetch under MFMA
    #pragma unroll
    for (int sp = 0; sp < 4; ++sp){
      const f64x2 a0 = *(const f64x2*)(As + (wm * 32 +  0 + m) * RSF + sp * 8 + q * 2);
      const f64x2 a1 = *(const f64x2*)(As + (wm * 32 + 16 + m) * RSF + sp * 8 + q * 2);
      const f64x2 b0 = *(const f64x2*)(Bs + (wn * 32 +  0 + m) * RSF + sp * 8 + q * 2);
      const f64x2 b1 = *(const f64x2*)(Bs + (wn * 32 + 16 + m) * RSF + sp * 8 + q * 2);
      acc[0][0] = __builtin_amdgcn_mfma_f64_16x16x4f64(a0[0], b0[0], acc[0][0], 0, 0, 0);
      acc[0][1] = __builtin_amdgcn_mfma_f64_16x16x4f64(a0[0], b1[0], acc[0][1], 0, 0, 0);
      acc[1][0] = __builtin_amdgcn_mfma_f64_16x16x4f64(a1[0], b0[0], acc[1][0], 0, 0, 0);
      acc[1][1] = __builtin_amdgcn_mfma_f64_16x16x4f64(a1[0], b1[0], acc[1][1], 0, 0, 0);
      acc[0][0] = __builtin_amdgcn_mfma_f64_16x16x4f64(a0[1], b0[1], acc[0][0], 0, 0, 0);
      acc[0][1] = __builtin_amdgcn_mfma_f64_16x16x4f64(a0[1], b1[1], acc[0][1], 0, 0, 0);
      acc[1][0] = __builtin_amdgcn_mfma_f64_16x16x4f64(a1[1], b0[1], acc[1][0], 0, 0, 0);
      acc[1][1] = __builtin_amdgcn_mfma_f64_16x16x4f64(a1[1], b1[1], acc[1][1], 0, 0, 0);
    }
  }
  // epilogue, HW-verified H2 layout: reg v -> row base + q + 4v, col base + m
  #pragma unroll
  for (int g = 0; g < 2; ++g){
    const int rb = rowb + wm * 32 + g * 16 + q;
    #pragma unroll
    for (int h = 0; h < 2; ++h){
      const int cc = colb + wn * 32 + h * 16 + m;
      if (BIAS){
        const double bb = (double)bih[cc] + (double)bhh[cc];
        #pragma unroll
        for (int v = 0; v < 4; ++v){
          if (OUT64) ((double*)outv)[(size_t)(rb + 4 * v) * G4 + cc] = acc[g][h][v] + bb;
          else       ((float*) outv)[(size_t)(rb + 4 * v) * G4 + cc] = (float)(acc[g][h][v] + bb);
        }
      } else {
        #pragma unroll
        for (int v = 0; v < 4; ++v){
          const size_t o = (size_t)(rb + 4 * v) * G4 + cc;
          if (OUT64) ((double*)outv)[o] = acc[g][h][v] + ((const double*)addin)[o];
          else       ((float*) outv)[o] = (float)(acc[g][h][v] + (double)((const float*)addin)[o]);
        }
      }
    }
  }
}

// ---------------- scalar f32 GEMM: 64x64 tile, 4x4/thread, k-chunk 64 (VALU pipe) ----------------
template <bool BIAS>
__device__ void dgemm32(char* smem, const float* __restrict__ A, int lda,
                        const float* __restrict__ B, int ldb,
                        int rowb, int colb, int K,
                        const float* __restrict__ addin,
                        const float* __restrict__ bih, const float* __restrict__ bhh,
                        float* __restrict__ outp){
  float* As = (float*)smem;                       // [64][FRS]
  float* Bs = (float*)(smem + 64 * FRS * 4);      // [64][FRS]
  const int tid = threadIdx.x;
  const int tx = tid & 15, ty = tid >> 4;         // rows 4ty..+3, cols 4tx..+3
  const int r_ = tid >> 2, kq = tid & 3;          // staging: row/col r_, 16 k at kq*16
  float acc[4][4];
  #pragma unroll
  for (int i = 0; i < 4; ++i)
    #pragma unroll
    for (int j = 0; j < 4; ++j) acc[i][j] = 0.f;

  float pa[16], pb[16];
  auto ldA = [&](int kb){
    const float* ap = A + (size_t)(rowb + r_) * lda + kb + kq * 16;
    #pragma unroll
    for (int j = 0; j < 16; ++j) pa[j] = ap[j];
  };
  auto ldB = [&](int kb){
    const float* bp = B + (size_t)(colb + r_) * ldb + kb + kq * 16;
    #pragma unroll
    for (int j = 0; j < 16; ++j) pb[j] = bp[j];
  };
  ldA(0); ldB(0);
  for (int kb = 0; kb < K; kb += 64){
    __syncthreads();
    #pragma unroll
    for (int j = 0; j < 16; ++j){
      As[(kq * 16 + j) * FRS + r_] = pa[j];
      Bs[(kq * 16 + j) * FRS + r_] = pb[j];
    }
    __syncthreads();
    if (kb + 64 < K){ ldA(kb + 64); ldB(kb + 64); }
    #pragma unroll 4
    for (int k = 0; k < 64; ++k){
      f32x4 a4 = *(const f32x4*)(As + k * FRS + 4 * ty);
      f32x4 b4 = *(const f32x4*)(Bs + k * FRS + 4 * tx);
      acc[0][0] = fmaf(a4[0], b4[0], acc[0][0]); acc[0][1] = fmaf(a4[0], b4[1], acc[0][1]);
      acc[0][2] = fmaf(a4[0], b4[2], acc[0][2]); acc[0][3] = fmaf(a4[0], b4[3], acc[0][3]);
      acc[1][0] = fmaf(a4[1], b4[0], acc[1][0]); acc[1][1] = fmaf(a4[1], b4[1], acc[1][1]);
      acc[1][2] = fmaf(a4[1], b4[2], acc[1][2]); acc[1][3] = fmaf(a4[1], b4[3], acc[1][3]);
      acc[2][0] = fmaf(a4[2], b4[0], acc[2][0]); acc[2][1] = fmaf(a4[2], b4[1], acc[2][1]);
      acc[2][2] = fmaf(a4[2], b4[2], acc[2][2]); acc[2][3] = fmaf(a4[2], b4[3], acc[2][3]);
      acc[3][0] = fmaf(a4[3], b4[0], acc[3][0]); acc[3][1] = fmaf(a4[3], b4[1], acc[3][1]);
      acc[3][2] = fmaf(a4[3], b4[2], acc[3][2]); acc[3][3] = fmaf(a4[3], b4[3], acc[3][3]);
    }
  }
  const int c0 = colb + 4 * tx;
  if (BIAS){
    float bb0 = bih[c0+0] + bhh[c0+0], bb1 = bih[c0+1] + bhh[c0+1];
    float bb2 = bih[c0+2] + bhh[c0+2], bb3 = bih[c0+3] + bhh[c0+3];
    #pragma unroll
    for (int i = 0; i < 4; ++i){
      float* o = outp + (size_t)(rowb + 4 * ty + i) * G4 + c0;
      o[0] = acc[i][0] + bb0; o[1] = acc[i][1] + bb1;
      o[2] = acc[i][2] + bb2; o[3] = acc[i][3] + bb3;
    }
  } else {
    #pragma unroll
    for (int i = 0; i < 4; ++i){
      const size_t base = (size_t)(rowb + 4 * ty + i) * G4 + c0;
      const float* ai = addin + base;
      float* o = outp + base;
      o[0] = acc[i][0] + ai[0]; o[1] = acc[i][1] + ai[1];
      o[2] = acc[i][2] + ai[2]; o[3] = acc[i][3] + ai[3];
    }
  }
}

// ---------------- ts head, j-split (relu-safe): 512 jobs of 8 j-rows ----------------
__device__ void tshead_j(const P& p, int bid, int hbuf){
  const int tid = threadIdx.x;
  const int tm = bid >> 6, tjq = bid & 63;
  const int rowb = tm * 32;
  const int rt = tid >> 3, j8 = tid & 7;
  const int j = tjq * 8 + j8;
  const float* __restrict__ hr = p.h_t + (size_t)hbuf * BB * CF + (size_t)(rowb + rt) * CF;
  const float* __restrict__ wr = p.W_ts1 + (size_t)j * CF;
  float a0=0,a1=0,a2=0,a3=0;
  for (int k = 0; k < CF; k += 16){
    f32x4 h0 = *(const f32x4*)(hr + k),     h1 = *(const f32x4*)(hr + k + 4);
    f32x4 h2 = *(const f32x4*)(hr + k + 8), h3 = *(const f32x4*)(hr + k + 12);
    f32x4 w0 = *(const f32x4*)(wr + k),     w1 = *(const f32x4*)(wr + k + 4);
    f32x4 w2 = *(const f32x4*)(wr + k + 8), w3 = *(const f32x4*)(wr + k + 12);
    a0 = fmaf(h0[0],w0[0], fmaf(h0[1],w0[1], fmaf(h0[2],w0[2], fmaf(h0[3],w0[3], a0))));
    a1 = fmaf(h1[0],w1[0], fmaf(h1[1],w1[1], fmaf(h1[2],w1[2], fmaf(h1[3],w1[3], a1))));
    a2 = fmaf(h2[0],w2[0], fmaf(h2[1],w2[1], fmaf(h2[2],w2[2], fmaf(h2[3],w2[3], a2))));
    a3 = fmaf(h3[0],w3[0], fmaf(h3[1],w3[1], fmaf(h3[2],w3[2], fmaf(h3[3],w3[3], a3))));
  }
  float v = ((a0 + a1) + (a2 + a3)) + p.b_ts1[j];
  v = (v > 0.f ? v : 0.f) * p.W_ts2[j];
  v += __shfl_xor(v, 1, 64);
  v += __shfl_xor(v, 2, 64);
  v += __shfl_xor(v, 4, 64);
  if (j8 == 0) atomicAdd(p.ts_accum + rowb + rt, v);
}

// ---------------- pre kernel. grid 512: half 0 = a (f64 MFMA), half 1 = t (f32 VALU) ----------------
__global__ void __launch_bounds__(NT) k_pre(P p){
  __shared__ __align__(16) char smem[SMEMB];
  const int bid = blockIdx.x;
  const int hsel = bid >> 8, sub = bid & 255;
  const int rowb = (sub >> 6) * 64, colb = (sub & 63) * 64;
  if (hsel == 0)
    mgemm64<true, true, true>(smem, p.t_rec64, TD, p.Wih_a, 768, rowb, colb, TD,
                              nullptr, p.bih_a, p.bhh_a, p.pre_a64);
  else
    dgemm32<true>(smem, p.t_rec32, TD, p.Wih_t, 769, rowb, colb, TD,
                  nullptr, p.bih_t, p.bhh_t, p.pre_t);
}

// ---------------- step A: ts head + recurrent GEMMs. grid 512 ----------------
// a-half on the MFMA pipe, t-half on the VALU pipe; pairs (sub, sub+256) share an XCD/CU
// so the two pipes overlap (m114: time ~ max, not sum).
__global__ void __launch_bounds__(NT) k_stepA(P p, int s){
  __shared__ __align__(16) char smem[SMEMB];
  const int bid = blockIdx.x;
  if (s > 0) tshead_j(p, bid, s & 1);           // ts head for step s-1 (no LDS)
  const int hsel = bid >> 8, sub = bid & 255;
  const int rowb = (sub >> 6) * 64, colb = (sub & 63) * 64;   // colb fast -> XCD-stable
  const int rd = s & 1;
  if (hsel == 0)
    mgemm64<true, true, false>(smem, p.h_a64 + (size_t)rd * BB * CF, CF, p.Whh_a, CF,
                               rowb, colb, CF, p.pre_a64, nullptr, nullptr, p.gacc_a);
  else
    dgemm32<false>(smem, p.h_t + (size_t)rd * BB * CF, CF, p.Whh_t, CF,
                   rowb, colb, CF, p.pre_t, nullptr, nullptr, p.gacc_t);
}

// ---------------- step B: LSTM-a pointwise (f64) + logits/argmax/softmax (f64) + LSTM-t (f32) ----------------
__global__ void __launch_bounds__(NT) k_stepB(P p, int s){
  __shared__ double shd[1092];
  const int b = blockIdx.x, tid = threadIdx.x;
  const int cur = (s + 1) & 1;   // h_a/h_t write buffer
  int idxp = p.idxb[b];
  idxp = idxp < 0 ? 0 : (idxp > 63 ? 63 : idxp);
  {
    const double* ga = p.gacc_a + (size_t)b * G4;       // includes pre_a (biases folded)
    const double* ea = p.E_proj_a64 + (size_t)idxp * G4;
    const int c0 = tid * 4;
    #pragma unroll
    for (int jj = 0; jj < 4; ++jj){
      const int c = c0 + jj;
      double gi = ga[0*CF + c] + ea[0*CF + c];
      double gf = ga[1*CF + c] + ea[1*CF + c];
      double gg = ga[2*CF + c] + ea[2*CF + c];
      double go = ga[3*CF + c] + ea[3*CF + c];
      double cv = p.c_a64[(size_t)b * CF + c];
      double cn = sigd(gf) * cv + sigd(gi) * tanh(gg);
      double hn = sigd(go) * tanh(cn);
      p.c_a64[(size_t)b * CF + c] = cn;
      p.h_a64[(size_t)cur * BB * CF + (size_t)b * CF + c] = hn;
      shd[c] = hn;
    }
  }
  if (tid == 0) shd[1088] = (s == 0) ? 0.0 : ((double)p.ts_accum[b] + (double)p.b_ts2[0]);
  __syncthreads();
  {
    const int w = tid >> 6, l = tid & 63, l15 = l & 15, quad = l >> 4;
    const int a = w * 16 + l15;
    const float* wr = p.W_act + (size_t)a * CF + quad * 256;
    const double* hp = shd + quad * 256;
    double acc = 0.0;
    for (int kk = 0; kk < 256; kk += 4){
      acc = fma((double)wr[kk+0], hp[kk+0], acc);
      acc = fma((double)wr[kk+1], hp[kk+1], acc);
      acc = fma((double)wr[kk+2], hp[kk+2], acc);
      acc = fma((double)wr[kk+3], hp[kk+3], acc);
    }
    acc += __shfl_xor(acc, 16, 64);
    acc += __shfl_xor(acc, 32, 64);
    if (quad == 0) shd[1024 + a] = acc;
  }
  __syncthreads();
  if (tid < 64){
    double acc = shd[1024 + tid] + (double)p.b_act[tid];
    double m = acc;
    #pragma unroll
    for (int off = 32; off; off >>= 1) m = fmax(m, __shfl_xor(m, off, 64));
    unsigned long long ball = __ballot(acc == m);
    int idxv = __ffsll(ball) - 1;               // first max == np.argmax
    idxv = idxv < 0 ? 0 : (idxv > 63 ? 63 : idxv);
    double e = exp(acc - m);
    double ssum = e;
    #pragma unroll
    for (int off = 32; off; off >>= 1) ssum += __shfl_xor(ssum, off, 64);
    p.out[(size_t)b * (NSTEP * NA) + s * NA + tid] = (float)(e / ssum);
    if (tid == 0){
      p.idxb[b] = idxv;
      shd[1089] = (double)idxv;
      if (s > 0) p.out[TS_OFF + b * NSTEP + (s - 1)] = (float)shd[1088];
    }
  }
  __syncthreads();
  const float ts_val = (float)shd[1088];
  const int idxv = (int)shd[1089];
  const int c0 = tid * 4;
  const float* gb = p.gacc_t   + (size_t)b * G4;   // includes pre_t (biases folded)
  const float* eb = p.E_proj_t + (size_t)idxv * G4;
  f32x4 gi = *(const f32x4*)(gb + 0*CF + c0) + *(const f32x4*)(eb + 0*CF + c0) + ts_val * *(const f32x4*)(p.colt + 0*CF + c0);
  f32x4 gf = *(const f32x4*)(gb + 1*CF + c0) + *(const f32x4*)(eb + 1*CF + c0) + ts_val * *(const f32x4*)(p.colt + 1*CF + c0);
  f32x4 gg = *(const f32x4*)(gb + 2*CF + c0) + *(const f32x4*)(eb + 2*CF + c0) + ts_val * *(const f32x4*)(p.colt + 2*CF + c0);
  f32x4 go = *(const f32x4*)(gb + 3*CF + c0) + *(const f32x4*)(eb + 3*CF + c0) + ts_val * *(const f32x4*)(p.colt + 3*CF + c0);
  f32x4 cv = *(f32x4*)(p.c_t + (size_t)b * CF + c0);
  f32x4 cn, hn;
  #pragma unroll
  for (int jj = 0; jj < 4; ++jj){
    float cj = sigf(gf[jj]) * cv[jj] + sigf(gi[jj]) * tanhf_(gg[jj]);
    float hj = sigf(go[jj]) * tanhf_(cj);
    cn[jj] = cj; hn[jj] = hj;
  }
  *(f32x4*)(p.c_t + (size_t)b * CF + c0) = cn;
  *(f32x4*)(p.h_t + (size_t)cur * BB * CF + (size_t)b * CF + c0) = hn;
  __syncthreads();
  if (tid == 0) p.ts_accum[b] = 0.f;   // ready for next step's tshead accumulation
}

// final ts head for step 63 (h_t buffer 0) + write
__global__ void __launch_bounds__(NT) k_tsfin(P p){
  tshead_j(p, blockIdx.x, 0);
}
__global__ void __launch_bounds__(NT) k_tswrite(P p){
  p.out[TS_OFF + threadIdx.x * NSTEP + 63] = p.ts_accum[threadIdx.x] + p.b_ts2[0];
}

extern "C" void kernel_launch(void* const* d_in, const int* in_sizes, int n_in,
                              void* d_out, int out_size, void* d_ws, size_t ws_size,
                              hipStream_t stream){
  (void)in_sizes; (void)n_in; (void)out_size; (void)ws_size;
  P p;
  p.z     = (const float*)d_in[0];  p.W_z2t = (const float*)d_in[1];  p.b_z2t = (const float*)d_in[2];
  p.E     = (const float*)d_in[3];  p.Wih_a = (const float*)d_in[4];  p.Whh_a = (const float*)d_in[5];
  p.bih_a = (const float*)d_in[6];  p.bhh_a = (const float*)d_in[7];  p.Wih_t = (const float*)d_in[8];
  p.Whh_t = (const float*)d_in[9];  p.bih_t = (const float*)d_in[10]; p.bhh_t = (const float*)d_in[11];
  p.W_act = (const float*)d_in[12]; p.b_act = (const float*)d_in[13]; p.W_ts1 = (const float*)d_in[14];
  p.b_ts1 = (const float*)d_in[15]; p.W_ts2 = (const float*)d_in[16]; p.b_ts2 = (const float*)d_in[17];
  p.out = (float*)d_out;
  char* w = (char*)d_ws;
  size_t off = 0;
  auto alloc = [&](size_t bytes) -> void* { void* r = w + off; off += (bytes + 255) & ~(size_t)255; return r; };
  p.t_rec64    = (double*)alloc((size_t)BB * TD * 8);
  p.pre_a64    = (double*)alloc((size_t)BB * G4 * 8);
  p.E_proj_a64 = (double*)alloc((size_t)NA * G4 * 8);
  p.h_a64      = (double*)alloc((size_t)2 * BB * CF * 8);
  p.c_a64      = (double*)alloc((size_t)BB * CF * 8);
  p.gacc_a     = (double*)alloc((size_t)BB * G4 * 8);
  p.t_rec32    = (float*)alloc((size_t)BB * TD * 4);
  p.pre_t      = (float*)alloc((size_t)BB * G4 * 4);
  p.E_proj_t   = (float*)alloc((size_t)NA * G4 * 4);
  p.colt       = (float*)alloc((size_t)G4 * 4);
  p.h_t        = (float*)alloc((size_t)2 * BB * CF * 4);
  p.c_t        = (float*)alloc((size_t)BB * CF * 4);
  p.gacc_t     = (float*)alloc((size_t)BB * G4 * 4);
  p.ts_accum   = (float*)alloc((size_t)BB * 4);
  p.idxb       = (int*)  alloc((size_t)BB * 4);

  k_setup<<<dim3(256), dim3(NT), 0, stream>>>(p);
  k_eproj<<<dim3(528), dim3(NT), 0, stream>>>(p);
  k_pre  <<<dim3(512), dim3(NT), 0, stream>>>(p);
  for (int s = 0; s < NSTEP; ++s){
    k_stepA<<<dim3(512), dim3(NT), 0, stream>>>(p, s);
    k_stepB<<<dim3(256), dim3(NT), 0, stream>>>(p, s);
  }
  k_tsfin  <<<dim3(512), dim3(NT), 0, stream>>>(p);
  k_tswrite<<<dim3(1),   dim3(NT), 0, stream>>>(p);
}

// Round 11
// 12154.234 us; speedup vs baseline: 1.8846x; 1.8846x over previous
//
#include <hip/hip_runtime.h>
#include <stdint.h>

typedef unsigned int u32;
typedef float  f32x4 __attribute__((ext_vector_type(4)));
typedef float  f32x2 __attribute__((ext_vector_type(2)));
typedef double f64x2 __attribute__((ext_vector_type(2)));
typedef double f64x4 __attribute__((ext_vector_type(4)));

constexpr int NT = 256;   // threads per block
constexpr int BB = 256;   // batch
constexpr int ZD = 256;
constexpr int TD = 512;
constexpr int CF = 1024;
constexpr int G4 = 4096;
constexpr int NA = 64;
constexpr int NSTEP = 64;
constexpr int TS_OFF = BB * NSTEP * NA;   // acts [256][64][64] then ts [256][64]

// f64 MFMA GEMM. HW-VERIFIED (round-2 probe, H2): D(lane=16q+m, reg v) -> row q+4v, col m.
// ALIGNMENT RULE (round-10 measured: odd strides -> b128 split to b64/b32, 2x slowdown):
// f64 row strides must be EVEN (16B rows), f32 strides even (8B rows).
// k_pre core: BK=32, RSF=34 (16B-aligned, round-3/6 proven, 34816 B LDS).
constexpr int RSF = 34;
// stepA core: BK=64, A f64 stride 66 (528B rows, 16B-aligned), B f32 stride 66 (264B, 8B-aligned).
constexpr int RSA   = 66;
constexpr int RBD   = 66;
constexpr int ATILE = 64 * RSA * 8;            // 33792 B
constexpr int BTILE = 64 * RBD * 4;            // 16896 B
constexpr int BSMEM = ATILE + BTILE;           // 50688 B  (< 64 KB static limit)
constexpr int PSMEM = 2 * 64 * RSF * 8;        // 34816 B  (k_pre)

struct P {
  const float *z, *W_z2t, *b_z2t, *E, *Wih_a, *Whh_a, *bih_a, *bhh_a,
              *Wih_t, *Whh_t, *bih_t, *bhh_t, *W_act, *b_act, *W_ts1, *b_ts1, *W_ts2, *b_ts2;
  float* out;                                               // float32 output (ref dtype)
  // f64 argmax-critical path
  double *t_rec64, *pre_a64, *E_proj_a64, *h_a64, *c_a64, *gacc_a;  // h_a64 dbuf [2][256][1024]
  // f32 ts path
  float *t_rec32, *pre_t, *E_proj_t, *colt, *h_t, *c_t, *gacc_t, *ts_accum;  // h_t dbuf [2][..]
  int* idxb;
};

__device__ __forceinline__ float sigf(float x){ return 1.f / (1.f + expf(-x)); }
__device__ __forceinline__ float tanhf_(float x){
  float ax = fabsf(x); float e = expf(-2.f * ax);
  float t = 1.f - 2.f * e / (1.f + e);
  return x < 0.f ? -t : t;
}
__device__ __forceinline__ double sigd(double x){ return 1.0 / (1.0 + exp(-x)); }

// ---------------- setup: t_rec (f64+f32), state init ----------------
__global__ void __launch_bounds__(NT) k_setup(P p){
  __shared__ double sz[ZD];
  const int bid = blockIdx.x, tid = threadIdx.x;
  for (int i = tid; i < ZD; i += NT) sz[i] = (double)p.z[bid * ZD + i];
  __syncthreads();
  for (int k = tid; k < TD; k += NT){
    const float* wr = p.W_z2t + (size_t)k * ZD;
    double a = 0.0;
    for (int j = 0; j < ZD; ++j) a = fma((double)wr[j], sz[j], a);
    a += (double)p.b_z2t[k];
    double t = a > 0.0 ? a : 0.0;
    p.t_rec64[(size_t)bid * TD + k] = t;
    p.t_rec32[(size_t)bid * TD + k] = (float)t;
  }
  for (int i = tid; i < CF; i += NT){
    p.c_a64[(size_t)bid * CF + i] = 0.0;
    p.h_a64[(size_t)bid * CF + i] = 0.0;  // buffer 0
    p.c_t[(size_t)bid * CF + i] = 0.f;
    p.h_t[(size_t)bid * CF + i] = 0.f;    // buffer 0
  }
  if (tid == 0){ p.idxb[bid] = NA - 1; p.ts_accum[bid] = 0.f; }
}

// ---------------- E_proj tables + colt. grid 528 ----------------
__global__ void __launch_bounds__(NT) k_eproj(P p){
  __shared__ double sz[ZD];
  const int bid = blockIdx.x, tid = threadIdx.x;
  if (bid < 256){            // E_proj_a64: row bid>>2, col chunk bid&3 (1024 cols)
    const int erow = bid >> 2, cchunk = bid & 3;
    for (int i = tid; i < ZD; i += NT) sz[i] = (double)p.E[erow * ZD + i];
    __syncthreads();
    for (int ci = 0; ci < 4; ++ci){
      const int c = cchunk * 1024 + ci * 256 + tid;
      const float* wr = p.Wih_a + (size_t)c * 768 + 512;
      double a = 0.0;
      for (int j = 0; j < 256; ++j) a = fma((double)wr[j], sz[j], a);
      p.E_proj_a64[(size_t)erow * G4 + c] = a;
    }
  } else if (bid < 512){     // E_proj_t (f32)
    const int erow = (bid - 256) >> 2, cchunk = (bid - 256) & 3;
    for (int i = tid; i < ZD; i += NT) sz[i] = (double)p.E[erow * ZD + i];
    __syncthreads();
    for (int ci = 0; ci < 4; ++ci){
      const int c = cchunk * 1024 + ci * 256 + tid;
      const float* wr = p.Wih_t + (size_t)c * 769 + 512;
      float a = 0.f;
      for (int j = 0; j < 256; ++j) a = fmaf(wr[j], (float)sz[j], a);
      p.E_proj_t[(size_t)erow * G4 + c] = a;
    }
  } else {                   // colt
    const int c = (bid - 512) * 256 + tid;
    p.colt[c] = p.Wih_t[(size_t)c * 769 + 768];
  }
}

// ---------------- k_pre core: BK=32, RSF=34, B in f64 (round-3 proven) ----------------
template <bool A64, bool OUT64>
__device__ void mgemm64s(char* smem, const void* __restrict__ Av, int lda,
                         const float* __restrict__ B, int ldb,
                         int rowb, int colb, int K,
                         const float* __restrict__ bih, const float* __restrict__ bhh,
                         void* __restrict__ outv){
  double* As = (double*)smem;
  double* Bs = As + 64 * RSF;
  const int tid = threadIdx.x;
  const int lane = tid & 63;
  const int wm = (tid >> 7) & 1, wn = (tid >> 6) & 1;   // wave -> 2x2 grid of 32x32 tiles
  const int m = lane & 15, q = lane >> 4;
  const int tr = tid >> 2, tkq = tid & 3;               // staging: row/col tr, k-octet tkq
  const double* A64p = (const double*)Av;
  const float*  A32p = (const float*)Av;

  double av[8], bv[8];
  auto loadchunk = [&](int kb){
    if (A64){
      const double* ap = A64p + (size_t)(rowb + tr) * lda + kb + tkq * 8;
      #pragma unroll
      for (int j = 0; j < 8; ++j) av[j] = ap[j];
    } else {
      const float* ap = A32p + (size_t)(rowb + tr) * lda + kb + tkq * 8;
      #pragma unroll
      for (int j = 0; j < 8; ++j) av[j] = (double)ap[j];
    }
    const float* bp = B + (size_t)(colb + tr) * ldb + kb + tkq * 8;
    #pragma unroll
    for (int j = 0; j < 8; ++j) bv[j] = (double)bp[j];
  };
  f64x4 acc[2][2];
  #pragma unroll
  for (int g = 0; g < 2; ++g)
    #pragma unroll
    for (int h = 0; h < 2; ++h) acc[g][h] = f64x4{0.0,0.0,0.0,0.0};

  loadchunk(0);
  for (int kb = 0; kb < K; kb += 32){
    __syncthreads();
    {
      double* arow = As + tr * RSF + tkq * 8;
      double* brow = Bs + tr * RSF + tkq * 8;
      #pragma unroll
      for (int j = 0; j < 4; ++j){                // pair (k, k+4) -> adjacent slots
        *(f64x2*)(arow + j * 2) = f64x2{av[j], av[j + 4]};
        *(f64x2*)(brow + j * 2) = f64x2{bv[j], bv[j + 4]};
      }
    }
    __syncthreads();
    if (kb + 32 < K) loadchunk(kb + 32);          // register prefetch under MFMA
    #pragma unroll
    for (int sp = 0; sp < 4; ++sp){
      const f64x2 a0 = *(const f64x2*)(As + (wm * 32 +  0 + m) * RSF + sp * 8 + q * 2);
      const f64x2 a1 = *(const f64x2*)(As + (wm * 32 + 16 + m) * RSF + sp * 8 + q * 2);
      const f64x2 b0 = *(const f64x2*)(Bs + (wn * 32 +  0 + m) * RSF + sp * 8 + q * 2);
      const f64x2 b1 = *(const f64x2*)(Bs + (wn * 32 + 16 + m) * RSF + sp * 8 + q * 2);
      acc[0][0] = __builtin_amdgcn_mfma_f64_16x16x4f64(a0[0], b0[0], acc[0][0], 0, 0, 0);
      acc[0][1] = __builtin_amdgcn_mfma_f64_16x16x4f64(a0[0], b1[0], acc[0][1], 0, 0, 0);
      acc[1][0] = __builtin_amdgcn_mfma_f64_16x16x4f64(a1[0], b0[0], acc[1][0], 0, 0, 0);
      acc[1][1] = __builtin_amdgcn_mfma_f64_16x16x4f64(a1[0], b1[0], acc[1][1], 0, 0, 0);
      acc[0][0] = __builtin_amdgcn_mfma_f64_16x16x4f64(a0[1], b0[1], acc[0][0], 0, 0, 0);
      acc[0][1] = __builtin_amdgcn_mfma_f64_16x16x4f64(a0[1], b1[1], acc[0][1], 0, 0, 0);
      acc[1][0] = __builtin_amdgcn_mfma_f64_16x16x4f64(a1[1], b0[1], acc[1][0], 0, 0, 0);
      acc[1][1] = __builtin_amdgcn_mfma_f64_16x16x4f64(a1[1], b1[1], acc[1][1], 0, 0, 0);
    }
  }
  // epilogue, HW-verified H2 layout: reg v -> row base + q + 4v, col base + m
  #pragma unroll
  for (int g = 0; g < 2; ++g){
    const int rb = rowb + wm * 32 + g * 16 + q;
    #pragma unroll
    for (int h = 0; h < 2; ++h){
      const int cc = colb + wn * 32 + h * 16 + m;
      const double bb = (double)bih[cc] + (double)bhh[cc];
      #pragma unroll
      for (int v = 0; v < 4; ++v){
        if (OUT64) ((double*)outv)[(size_t)(rb + 4 * v) * G4 + cc] = acc[g][h][v] + bb;
        else       ((float*) outv)[(size_t)(rb + 4 * v) * G4 + cc] = (float)(acc[g][h][v] + bb);
      }
    }
  }
}

// ---------------- stepA core: BK=64, A f64 (RSA=66), B f32 (RBD=66), same schedule ----------------
// LDS k-permutation within a 64-k row: f64/f32 position S*8 + Q*2 + e holds k = 8S + Q + 4e
// (S=0..7, Q=0..3, e=0..1); read at sp*8+q*2 gives the (k=8sp+q, k=8sp+q+4) MFMA pair.
// k-accumulation order identical to the BK=32 core (ascending 8-blocks, pairs (k,k+4)).
template <bool A64, bool OUT64>
__device__ void mgemm64b(char* smem, const void* __restrict__ Av, int lda,
                         const float* __restrict__ B, int ldb,
                         int rowb, int colb, int K,
                         const void* __restrict__ addin, void* __restrict__ outv){
  double* As = (double*)smem;                    // [64][RSA]
  float*  Bs = (float*)(smem + ATILE);           // [64][RBD]
  const int tid = threadIdx.x, lane = tid & 63;
  const int wm = (tid >> 7) & 1, wn = (tid >> 6) & 1;   // wave -> 2x2 grid of 32x32 tiles
  const int m = lane & 15, q = lane >> 4;
  const int tr = tid >> 2, tkq = tid & 3;               // staging: row/col tr, 16 k at tkq*16
  const double* A64p = (const double*)Av;
  const float*  A32p = (const float*)Av;

  double av[16]; float bv[16];
  auto loadchunk = [&](int kb){
    if (A64){
      const double* ap = A64p + (size_t)(rowb + tr) * lda + kb + tkq * 16;
      #pragma unroll
      for (int j = 0; j < 16; ++j) av[j] = ap[j];
    } else {
      const float* ap = A32p + (size_t)(rowb + tr) * lda + kb + tkq * 16;
      #pragma unroll
      for (int j = 0; j < 16; ++j) av[j] = (double)ap[j];
    }
    const float* bp = B + (size_t)(colb + tr) * ldb + kb + tkq * 16;
    #pragma unroll
    for (int j = 0; j < 16; ++j) bv[j] = bp[j];
  };

  f64x4 acc[2][2];
  #pragma unroll
  for (int g = 0; g < 2; ++g)
    #pragma unroll
    for (int h = 0; h < 2; ++h) acc[g][h] = f64x4{0.0,0.0,0.0,0.0};

  loadchunk(0);
  for (int kb = 0; kb < K; kb += 64){
    __syncthreads();
    {
      double* arow = As + tr * RSA + tkq * 16;
      float*  brow = Bs + tr * RBD + tkq * 16;
      #pragma unroll
      for (int spl = 0; spl < 2; ++spl)
        #pragma unroll
        for (int qq = 0; qq < 4; ++qq){
          *(f64x2*)(arow + spl * 8 + qq * 2) = f64x2{av[spl * 8 + qq], av[spl * 8 + qq + 4]};
          *(f32x2*)(brow + spl * 8 + qq * 2) = f32x2{bv[spl * 8 + qq], bv[spl * 8 + qq + 4]};
        }
    }
    __syncthreads();
    if (kb + 64 < K) loadchunk(kb + 64);          // register prefetch under MFMA
    #pragma unroll
    for (int sp = 0; sp < 8; ++sp){
      const f64x2 a0 = *(const f64x2*)(As + (wm * 32 +  0 + m) * RSA + sp * 8 + q * 2);
      const f64x2 a1 = *(const f64x2*)(As + (wm * 32 + 16 + m) * RSA + sp * 8 + q * 2);
      const f32x2 b0f = *(const f32x2*)(Bs + (wn * 32 +  0 + m) * RBD + sp * 8 + q * 2);
      const f32x2 b1f = *(const f32x2*)(Bs + (wn * 32 + 16 + m) * RBD + sp * 8 + q * 2);
      const double b00 = (double)b0f[0], b04 = (double)b0f[1];
      const double b10 = (double)b1f[0], b14 = (double)b1f[1];
      acc[0][0] = __builtin_amdgcn_mfma_f64_16x16x4f64(a0[0], b00, acc[0][0], 0, 0, 0);
      acc[0][1] = __builtin_amdgcn_mfma_f64_16x16x4f64(a0[0], b10, acc[0][1], 0, 0, 0);
      acc[1][0] = __builtin_amdgcn_mfma_f64_16x16x4f64(a1[0], b00, acc[1][0], 0, 0, 0);
      acc[1][1] = __builtin_amdgcn_mfma_f64_16x16x4f64(a1[0], b10, acc[1][1], 0, 0, 0);
      acc[0][0] = __builtin_amdgcn_mfma_f64_16x16x4f64(a0[1], b04, acc[0][0], 0, 0, 0);
      acc[0][1] = __builtin_amdgcn_mfma_f64_16x16x4f64(a0[1], b14, acc[0][1], 0, 0, 0);
      acc[1][0] = __builtin_amdgcn_mfma_f64_16x16x4f64(a1[1], b04, acc[1][0], 0, 0, 0);
      acc[1][1] = __builtin_amdgcn_mfma_f64_16x16x4f64(a1[1], b14, acc[1][1], 0, 0, 0);
    }
  }
  // epilogue, HW-verified H2 layout: reg v -> row base + q + 4v, col base + m
  #pragma unroll
  for (int g = 0; g < 2; ++g){
    const int rb = rowb + wm * 32 + g * 16 + q;
    #pragma unroll
    for (int h = 0; h < 2; ++h){
      const int cc = colb + wn * 32 + h * 16 + m;
      #pragma unroll
      for (int v = 0; v < 4; ++v){
        const size_t o = (size_t)(rb + 4 * v) * G4 + cc;
        if (OUT64) ((double*)outv)[o] = acc[g][h][v] + ((const double*)addin)[o];
        else       ((float*) outv)[o] = (float)(acc[g][h][v] + (double)((const float*)addin)[o]);
      }
    }
  }
}

// ---------------- ts head, j-split (relu-safe): 512 jobs of 8 j-rows ----------------
__device__ void tshead_j(const P& p, int bid, int hbuf){
  const int tid = threadIdx.x;
  const int tm = bid >> 6, tjq = bid & 63;
  const int rowb = tm * 32;
  const int rt = tid >> 3, j8 = tid & 7;
  const int j = tjq * 8 + j8;
  const float* __restrict__ hr = p.h_t + (size_t)hbuf * BB * CF + (size_t)(rowb + rt) * CF;
  const float* __restrict__ wr = p.W_ts1 + (size_t)j * CF;
  float a0=0,a1=0,a2=0,a3=0;
  for (int k = 0; k < CF; k += 16){
    f32x4 h0 = *(const f32x4*)(hr + k),     h1 = *(const f32x4*)(hr + k + 4);
    f32x4 h2 = *(const f32x4*)(hr + k + 8), h3 = *(const f32x4*)(hr + k + 12);
    f32x4 w0 = *(const f32x4*)(wr + k),     w1 = *(const f32x4*)(wr + k + 4);
    f32x4 w2 = *(const f32x4*)(wr + k + 8), w3 = *(const f32x4*)(wr + k + 12);
    a0 = fmaf(h0[0],w0[0], fmaf(h0[1],w0[1], fmaf(h0[2],w0[2], fmaf(h0[3],w0[3], a0))));
    a1 = fmaf(h1[0],w1[0], fmaf(h1[1],w1[1], fmaf(h1[2],w1[2], fmaf(h1[3],w1[3], a1))));
    a2 = fmaf(h2[0],w2[0], fmaf(h2[1],w2[1], fmaf(h2[2],w2[2], fmaf(h2[3],w2[3], a2))));
    a3 = fmaf(h3[0],w3[0], fmaf(h3[1],w3[1], fmaf(h3[2],w3[2], fmaf(h3[3],w3[3], a3))));
  }
  float v = ((a0 + a1) + (a2 + a3)) + p.b_ts1[j];
  v = (v > 0.f ? v : 0.f) * p.W_ts2[j];
  v += __shfl_xor(v, 1, 64);
  v += __shfl_xor(v, 2, 64);
  v += __shfl_xor(v, 4, 64);
  if (j8 == 0) atomicAdd(p.ts_accum + rowb + rt, v);
}

// ---------------- pre kernel. grid 512: half 0 = a (f64), half 1 = t (f32 in/out) ----------------
__global__ void __launch_bounds__(NT) k_pre(P p){
  __shared__ __align__(16) char smem[PSMEM];
  const int bid = blockIdx.x;
  const int hsel = bid >> 8, sub = bid & 255;
  const int rowb = (sub >> 6) * 64, colb = (sub & 63) * 64;
  if (hsel == 0)
    mgemm64s<true, true>(smem, p.t_rec64, TD, p.Wih_a, 768, rowb, colb, TD,
                         p.bih_a, p.bhh_a, p.pre_a64);
  else
    mgemm64s<false, false>(smem, p.t_rec32, TD, p.Wih_t, 769, rowb, colb, TD,
                           p.bih_t, p.bhh_t, p.pre_t);
}

// ---------------- step A: ts head + both recurrent GEMMs (BK=64 MFMA). grid 512 ----------------
__global__ void __launch_bounds__(NT) k_stepA(P p, int s){
  __shared__ __align__(16) char smem[BSMEM];
  const int bid = blockIdx.x;
  if (s > 0) tshead_j(p, bid, s & 1);           // ts head for step s-1 (no LDS)
  const int hsel = bid >> 8, sub = bid & 255;
  const int rowb = (sub >> 6) * 64, colb = (sub & 63) * 64;   // colb fast -> XCD-stable
  const int rd = s & 1;
  if (hsel == 0)
    mgemm64b<true, true>(smem, p.h_a64 + (size_t)rd * BB * CF, CF, p.Whh_a, CF,
                         rowb, colb, CF, p.pre_a64, p.gacc_a);
  else
    mgemm64b<false, false>(smem, p.h_t + (size_t)rd * BB * CF, CF, p.Whh_t, CF,
                           rowb, colb, CF, p.pre_t, p.gacc_t);
}

// ---------------- step B: LSTM-a pointwise (f64) + logits/argmax/softmax (f64) + LSTM-t (f32) ----------------
__global__ void __launch_bounds__(NT) k_stepB(P p, int s){
  __shared__ double shd[1092];
  const int b = blockIdx.x, tid = threadIdx.x;
  const int cur = (s + 1) & 1;   // h_a/h_t write buffer
  int idxp = p.idxb[b];
  idxp = idxp < 0 ? 0 : (idxp > 63 ? 63 : idxp);
  {
    const double* ga = p.gacc_a + (size_t)b * G4;       // includes pre_a (biases folded)
    const double* ea = p.E_proj_a64 + (size_t)idxp * G4;
    const int c0 = tid * 4;
    #pragma unroll
    for (int jj = 0; jj < 4; ++jj){
      const int c = c0 + jj;
      double gi = ga[0*CF + c] + ea[0*CF + c];
      double gf = ga[1*CF + c] + ea[1*CF + c];
      double gg = ga[2*CF + c] + ea[2*CF + c];
      double go = ga[3*CF + c] + ea[3*CF + c];
      double cv = p.c_a64[(size_t)b * CF + c];
      double cn = sigd(gf) * cv + sigd(gi) * tanh(gg);
      double hn = sigd(go) * tanh(cn);
      p.c_a64[(size_t)b * CF + c] = cn;
      p.h_a64[(size_t)cur * BB * CF + (size_t)b * CF + c] = hn;
      shd[c] = hn;
    }
  }
  if (tid == 0) shd[1088] = (s == 0) ? 0.0 : ((double)p.ts_accum[b] + (double)p.b_ts2[0]);
  __syncthreads();
  {
    const int w = tid >> 6, l = tid & 63, l15 = l & 15, quad = l >> 4;
    const int a = w * 16 + l15;
    const float* wr = p.W_act + (size_t)a * CF + quad * 256;
    const double* hp = shd + quad * 256;
    double acc = 0.0;
    for (int kk = 0; kk < 256; kk += 4){
      acc = fma((double)wr[kk+0], hp[kk+0], acc);
      acc = fma((double)wr[kk+1], hp[kk+1], acc);
      acc = fma((double)wr[kk+2], hp[kk+2], acc);
      acc = fma((double)wr[kk+3], hp[kk+3], acc);
    }
    acc += __shfl_xor(acc, 16, 64);
    acc += __shfl_xor(acc, 32, 64);
    if (quad == 0) shd[1024 + a] = acc;
  }
  __syncthreads();
  if (tid < 64){
    double acc = shd[1024 + tid] + (double)p.b_act[tid];
    double m = acc;
    #pragma unroll
    for (int off = 32; off; off >>= 1) m = fmax(m, __shfl_xor(m, off, 64));
    unsigned long long ball = __ballot(acc == m);
    int idxv = __ffsll(ball) - 1;               // first max == np.argmax
    idxv = idxv < 0 ? 0 : (idxv > 63 ? 63 : idxv);
    double e = exp(acc - m);
    double ssum = e;
    #pragma unroll
    for (int off = 32; off; off >>= 1) ssum += __shfl_xor(ssum, off, 64);
    p.out[(size_t)b * (NSTEP * NA) + s * NA + tid] = (float)(e / ssum);
    if (tid == 0){
      p.idxb[b] = idxv;
      shd[1089] = (double)idxv;
      if (s > 0) p.out[TS_OFF + b * NSTEP + (s - 1)] = (float)shd[1088];
    }
  }
  __syncthreads();
  const float ts_val = (float)shd[1088];
  const int idxv = (int)shd[1089];
  const int c0 = tid * 4;
  const float* gb = p.gacc_t   + (size_t)b * G4;   // includes pre_t (biases folded)
  const float* eb = p.E_proj_t + (size_t)idxv * G4;
  f32x4 gi = *(const f32x4*)(gb + 0*CF + c0) + *(const f32x4*)(eb + 0*CF + c0) + ts_val * *(const f32x4*)(p.colt + 0*CF + c0);
  f32x4 gf = *(const f32x4*)(gb + 1*CF + c0) + *(const f32x4*)(eb + 1*CF + c0) + ts_val * *(const f32x4*)(p.colt + 1*CF + c0);
  f32x4 gg = *(const f32x4*)(gb + 2*CF + c0) + *(const f32x4*)(eb + 2*CF + c0) + ts_val * *(const f32x4*)(p.colt + 2*CF + c0);
  f32x4 go = *(const f32x4*)(gb + 3*CF + c0) + *(const f32x4*)(eb + 3*CF + c0) + ts_val * *(const f32x4*)(p.colt + 3*CF + c0);
  f32x4 cv = *(f32x4*)(p.c_t + (size_t)b * CF + c0);
  f32x4 cn, hn;
  #pragma unroll
  for (int jj = 0; jj < 4; ++jj){
    float cj = sigf(gf[jj]) * cv[jj] + sigf(gi[jj]) * tanhf_(gg[jj]);
    float hj = sigf(go[jj]) * tanhf_(cj);
    cn[jj] = cj; hn[jj] = hj;
  }
  *(f32x4*)(p.c_t + (size_t)b * CF + c0) = cn;
  *(f32x4*)(p.h_t + (size_t)cur * BB * CF + (size_t)b * CF + c0) = hn;
  __syncthreads();
  if (tid == 0) p.ts_accum[b] = 0.f;   // ready for next step's tshead accumulation
}

// final ts head for step 63 (h_t buffer 0) + write
__global__ void __launch_bounds__(NT) k_tsfin(P p){
  tshead_j(p, blockIdx.x, 0);
}
__global__ void __launch_bounds__(NT) k_tswrite(P p){
  p.out[TS_OFF + threadIdx.x * NSTEP + 63] = p.ts_accum[threadIdx.x] + p.b_ts2[0];
}

extern "C" void kernel_launch(void* const* d_in, const int* in_sizes, int n_in,
                              void* d_out, int out_size, void* d_ws, size_t ws_size,
                              hipStream_t stream){
  (void)in_sizes; (void)n_in; (void)out_size; (void)ws_size;
  P p;
  p.z     = (const float*)d_in[0];  p.W_z2t = (const float*)d_in[1];  p.b_z2t = (const float*)d_in[2];
  p.E     = (const float*)d_in[3];  p.Wih_a = (const float*)d_in[4];  p.Whh_a = (const float*)d_in[5];
  p.bih_a = (const float*)d_in[6];  p.bhh_a = (const float*)d_in[7];  p.Wih_t = (const float*)d_in[8];
  p.Whh_t = (const float*)d_in[9];  p.bih_t = (const float*)d_in[10]; p.bhh_t = (const float*)d_in[11];
  p.W_act = (const float*)d_in[12]; p.b_act = (const float*)d_in[13]; p.W_ts1 = (const float*)d_in[14];
  p.b_ts1 = (const float*)d_in[15]; p.W_ts2 = (const float*)d_in[16]; p.b_ts2 = (const float*)d_in[17];
  p.out = (float*)d_out;
  char* w = (char*)d_ws;
  size_t off = 0;
  auto alloc = [&](size_t bytes) -> void* { void* r = w + off; off += (bytes + 255) & ~(size_t)255; return r; };
  p.t_rec64    = (double*)alloc((size_t)BB * TD * 8);
  p.pre_a64    = (double*)alloc((size_t)BB * G4 * 8);
  p.E_proj_a64 = (double*)alloc((size_t)NA * G4 * 8);
  p.h_a64      = (double*)alloc((size_t)2 * BB * CF * 8);
  p.c_a64      = (double*)alloc((size_t)BB * CF * 8);
  p.gacc_a     = (double*)alloc((size_t)BB * G4 * 8);
  p.t_rec32    = (float*)alloc((size_t)BB * TD * 4);
  p.pre_t      = (float*)alloc((size_t)BB * G4 * 4);
  p.E_proj_t   = (float*)alloc((size_t)NA * G4 * 4);
  p.colt       = (float*)alloc((size_t)G4 * 4);
  p.h_t        = (float*)alloc((size_t)2 * BB * CF * 4);
  p.c_t        = (float*)alloc((size_t)BB * CF * 4);
  p.gacc_t     = (float*)alloc((size_t)BB * G4 * 4);
  p.ts_accum   = (float*)alloc((size_t)BB * 4);
  p.idxb       = (int*)  alloc((size_t)BB * 4);

  k_setup<<<dim3(256), dim3(NT), 0, stream>>>(p);
  k_eproj<<<dim3(528), dim3(NT), 0, stream>>>(p);
  k_pre  <<<dim3(512), dim3(NT), 0, stream>>>(p);
  for (int s = 0; s < NSTEP; ++s){
    k_stepA<<<dim3(512), dim3(NT), 0, stream>>>(p, s);
    k_stepB<<<dim3(256), dim3(NT), 0, stream>>>(p, s);
  }
  k_tsfin  <<<dim3(512), dim3(NT), 0, stream>>>(p);
  k_tswrite<<<dim3(1),   dim3(NT), 0, stream>>>(p);
}

// Round 12
// 11420.318 us; speedup vs baseline: 2.0057x; 1.0643x over previous
//
#include <hip/hip_runtime.h>
#include <stdint.h>

typedef unsigned int u32;
typedef float  f32x4 __attribute__((ext_vector_type(4)));
typedef float  f32x2 __attribute__((ext_vector_type(2)));
typedef double f64x2 __attribute__((ext_vector_type(2)));
typedef double f64x4 __attribute__((ext_vector_type(4)));

constexpr int NT = 256;   // threads per block
constexpr int BB = 256;   // batch
constexpr int ZD = 256;
constexpr int TD = 512;
constexpr int CF = 1024;
constexpr int G4 = 4096;
constexpr int NA = 64;
constexpr int NSTEP = 64;
constexpr int TS_OFF = BB * NSTEP * NA;   // acts [256][64][64] then ts [256][64]

// f64 MFMA GEMM: 64x64 tile, 4 waves of 32x32, k-chunk 32 (round-3 structure, 170 us).
// HW-VERIFIED (round-2 probe, H2): D(lane=16q+m, reg v) -> row q+4v, col m.
// ALIGNMENT RULE (round-10 measured): LDS vector ops need 16B-aligned strides; odd
// element-strides split b128 -> b64/b32 (2x slowdown). RSF=34 f64 = 272B rows, aligned.
constexpr int RSF = 34;
// dgemm32 stride 68 f32 (272B, aligned). Bank fix is a XOR-swizzle (col ^ 8*kq), NOT an
// odd stride: keeps f32x4 16B alignment, breaks the kq-collapse 4-way write conflict
// (68*16 = 0 mod 32 made all kq groups hit the same bank; round-3's 7.34M conflict cyc).
constexpr int FRS = 68;
constexpr int SMEMB = 2 * 64 * RSF * 8;   // 34816 B (mgemm64); dgemm32 uses 2*64*68*4 = 34816 B

struct P {
  const float *z, *W_z2t, *b_z2t, *E, *Wih_a, *Whh_a, *bih_a, *bhh_a,
              *Wih_t, *Whh_t, *bih_t, *bhh_t, *W_act, *b_act, *W_ts1, *b_ts1, *W_ts2, *b_ts2;
  float* out;                                               // float32 output (ref dtype)
  // f64 argmax-critical path
  double *t_rec64, *pre_a64, *E_proj_a64, *h_a64, *c_a64, *gacc_a;  // h_a64 dbuf [2][256][1024]
  // f32 ts path
  float *t_rec32, *pre_t, *E_proj_t, *colt, *h_t, *c_t, *gacc_t, *ts_accum;  // h_t dbuf [2][..]
  int* idxb;
};

__device__ __forceinline__ float sigf(float x){ return 1.f / (1.f + expf(-x)); }
__device__ __forceinline__ float tanhf_(float x){
  float ax = fabsf(x); float e = expf(-2.f * ax);
  float t = 1.f - 2.f * e / (1.f + e);
  return x < 0.f ? -t : t;
}
__device__ __forceinline__ double sigd(double x){ return 1.0 / (1.0 + exp(-x)); }

// ---------------- setup: t_rec (f64+f32), state init ----------------
__global__ void __launch_bounds__(NT) k_setup(P p){
  __shared__ double sz[ZD];
  const int bid = blockIdx.x, tid = threadIdx.x;
  for (int i = tid; i < ZD; i += NT) sz[i] = (double)p.z[bid * ZD + i];
  __syncthreads();
  for (int k = tid; k < TD; k += NT){
    const float* wr = p.W_z2t + (size_t)k * ZD;
    double a = 0.0;
    for (int j = 0; j < ZD; ++j) a = fma((double)wr[j], sz[j], a);
    a += (double)p.b_z2t[k];
    double t = a > 0.0 ? a : 0.0;
    p.t_rec64[(size_t)bid * TD + k] = t;
    p.t_rec32[(size_t)bid * TD + k] = (float)t;
  }
  for (int i = tid; i < CF; i += NT){
    p.c_a64[(size_t)bid * CF + i] = 0.0;
    p.h_a64[(size_t)bid * CF + i] = 0.0;  // buffer 0
    p.c_t[(size_t)bid * CF + i] = 0.f;
    p.h_t[(size_t)bid * CF + i] = 0.f;    // buffer 0
  }
  if (tid == 0){ p.idxb[bid] = NA - 1; p.ts_accum[bid] = 0.f; }
}

// ---------------- E_proj tables + colt. grid 528 ----------------
__global__ void __launch_bounds__(NT) k_eproj(P p){
  __shared__ double sz[ZD];
  const int bid = blockIdx.x, tid = threadIdx.x;
  if (bid < 256){            // E_proj_a64: row bid>>2, col chunk bid&3 (1024 cols)
    const int erow = bid >> 2, cchunk = bid & 3;
    for (int i = tid; i < ZD; i += NT) sz[i] = (double)p.E[erow * ZD + i];
    __syncthreads();
    for (int ci = 0; ci < 4; ++ci){
      const int c = cchunk * 1024 + ci * 256 + tid;
      const float* wr = p.Wih_a + (size_t)c * 768 + 512;
      double a = 0.0;
      for (int j = 0; j < 256; ++j) a = fma((double)wr[j], sz[j], a);
      p.E_proj_a64[(size_t)erow * G4 + c] = a;
    }
  } else if (bid < 512){     // E_proj_t (f32)
    const int erow = (bid - 256) >> 2, cchunk = (bid - 256) & 3;
    for (int i = tid; i < ZD; i += NT) sz[i] = (double)p.E[erow * ZD + i];
    __syncthreads();
    for (int ci = 0; ci < 4; ++ci){
      const int c = cchunk * 1024 + ci * 256 + tid;
      const float* wr = p.Wih_t + (size_t)c * 769 + 512;
      float a = 0.f;
      for (int j = 0; j < 256; ++j) a = fmaf(wr[j], (float)sz[j], a);
      p.E_proj_t[(size_t)erow * G4 + c] = a;
    }
  } else {                   // colt
    const int c = (bid - 512) * 256 + tid;
    p.colt[c] = p.Wih_t[(size_t)c * 769 + 768];
  }
}

// ---------------- f64 MFMA GEMM: 64x64 tile. HW-verified core (round-2 probe, H2) ----------------
// A f64 (A64) or f32 rows (lda), B f32 rows (ldb), K mult of 32. Per-row LDS k-permutation:
// write pair (k, k+4) to adjacent f64 slots; read at sp*8+q*2 gives the (k=8sp+q, k=8sp+q+4)
// MFMA pair for lane quadrant q.
template <bool A64, bool OUT64, bool BIAS>
__device__ void mgemm64(char* smem, const void* __restrict__ Av, int lda,
                        const float* __restrict__ B, int ldb,
                        int rowb, int colb, int K,
                        const void* __restrict__ addin,
                        const float* __restrict__ bih, const float* __restrict__ bhh,
                        void* __restrict__ outv){
  double* As = (double*)smem;
  double* Bs = As + 64 * RSF;
  const int tid = threadIdx.x;
  const int lane = tid & 63;
  const int wm = (tid >> 7) & 1, wn = (tid >> 6) & 1;   // wave -> 2x2 grid of 32x32 tiles
  const int m = lane & 15, q = lane >> 4;
  const int tr = tid >> 2, tkq = tid & 3;               // staging: row/col tr, k-octet tkq
  const double* A64p = (const double*)Av;
  const float*  A32p = (const float*)Av;

  double av[8], bv[8];
  auto loadchunk = [&](int kb){
    if (A64){
      const double* ap = A64p + (size_t)(rowb + tr) * lda + kb + tkq * 8;
      #pragma unroll
      for (int j = 0; j < 8; ++j) av[j] = ap[j];
    } else {
      const float* ap = A32p + (size_t)(rowb + tr) * lda + kb + tkq * 8;
      #pragma unroll
      for (int j = 0; j < 8; ++j) av[j] = (double)ap[j];
    }
    const float* bp = B + (size_t)(colb + tr) * ldb + kb + tkq * 8;
    #pragma unroll
    for (int j = 0; j < 8; ++j) bv[j] = (double)bp[j];
  };
  f64x4 acc[2][2];
  #pragma unroll
  for (int g = 0; g < 2; ++g)
    #pragma unroll
    for (int h = 0; h < 2; ++h) acc[g][h] = f64x4{0.0,0.0,0.0,0.0};

  loadchunk(0);
  for (int kb = 0; kb < K; kb += 32){
    __syncthreads();
    {
      double* arow = As + tr * RSF + tkq * 8;
      double* brow = Bs + tr * RSF + tkq * 8;
      #pragma unroll
      for (int j = 0; j < 4; ++j){                // pair (k, k+4) -> adjacent slots
        *(f64x2*)(arow + j * 2) = f64x2{av[j], av[j + 4]};
        *(f64x2*)(brow + j * 2) = f64x2{bv[j], bv[j + 4]};
      }
    }
    __syncthreads();
    if (kb + 32 < K) loadchunk(kb + 32);          // register prefetch under MFMA
    #pragma unroll
    for (int sp = 0; sp < 4; ++sp){
      const f64x2 a0 = *(const f64x2*)(As + (wm * 32 +  0 + m) * RSF + sp * 8 + q * 2);
      const f64x2 a1 = *(const f64x2*)(As + (wm * 32 + 16 + m) * RSF + sp * 8 + q * 2);
      const f64x2 b0 = *(const f64x2*)(Bs + (wn * 32 +  0 + m) * RSF + sp * 8 + q * 2);
      const f64x2 b1 = *(const f64x2*)(Bs + (wn * 32 + 16 + m) * RSF + sp * 8 + q * 2);
      acc[0][0] = __builtin_amdgcn_mfma_f64_16x16x4f64(a0[0], b0[0], acc[0][0], 0, 0, 0);
      acc[0][1] = __builtin_amdgcn_mfma_f64_16x16x4f64(a0[0], b1[0], acc[0][1], 0, 0, 0);
      acc[1][0] = __builtin_amdgcn_mfma_f64_16x16x4f64(a1[0], b0[0], acc[1][0], 0, 0, 0);
      acc[1][1] = __builtin_amdgcn_mfma_f64_16x16x4f64(a1[0], b1[0], acc[1][1], 0, 0, 0);
      acc[0][0] = __builtin_amdgcn_mfma_f64_16x16x4f64(a0[1], b0[1], acc[0][0], 0, 0, 0);
      acc[0][1] = __builtin_amdgcn_mfma_f64_16x16x4f64(a0[1], b1[1], acc[0][1], 0, 0, 0);
      acc[1][0] = __builtin_amdgcn_mfma_f64_16x16x4f64(a1[1], b0[1], acc[1][0], 0, 0, 0);
      acc[1][1] = __builtin_amdgcn_mfma_f64_16x16x4f64(a1[1], b1[1], acc[1][1], 0, 0, 0);
    }
  }
  // epilogue, HW-verified H2 layout: reg v -> row base + q + 4v, col base + m
  #pragma unroll
  for (int g = 0; g < 2; ++g){
    const int rb = rowb + wm * 32 + g * 16 + q;
    #pragma unroll
    for (int h = 0; h < 2; ++h){
      const int cc = colb + wn * 32 + h * 16 + m;
      if (BIAS){
        const double bb = (double)bih[cc] + (double)bhh[cc];
        #pragma unroll
        for (int v = 0; v < 4; ++v){
          if (OUT64) ((double*)outv)[(size_t)(rb + 4 * v) * G4 + cc] = acc[g][h][v] + bb;
          else       ((float*) outv)[(size_t)(rb + 4 * v) * G4 + cc] = (float)(acc[g][h][v] + bb);
        }
      } else {
        #pragma unroll
        for (int v = 0; v < 4; ++v){
          const size_t o = (size_t)(rb + 4 * v) * G4 + cc;
          if (OUT64) ((double*)outv)[o] = acc[g][h][v] + ((const double*)addin)[o];
          else       ((float*) outv)[o] = (float)(acc[g][h][v] + (double)((const float*)addin)[o]);
        }
      }
    }
  }
}

// ---------------- scalar f32 GEMM: 64x64 tile, 4x4/thread, k-chunk 64 (VALU pipe) ----------------
// XOR swizzle (col ^ 8*kq) on LDS store/load: breaks the 4-way staging-write conflict while
// keeping 16B alignment (XOR with multiples of 8 preserves f32x4 blocks). Values unchanged.
template <bool BIAS>
__device__ void dgemm32(char* smem, const float* __restrict__ A, int lda,
                        const float* __restrict__ B, int ldb,
                        int rowb, int colb, int K,
                        const float* __restrict__ addin,
                        const float* __restrict__ bih, const float* __restrict__ bhh,
                        float* __restrict__ outp){
  float* As = (float*)smem;                       // [64][FRS]
  float* Bs = (float*)(smem + 64 * FRS * 4);      // [64][FRS]
  const int tid = threadIdx.x;
  const int tx = tid & 15, ty = tid >> 4;         // rows 4ty..+3, cols 4tx..+3
  const int r_ = tid >> 2, kq = tid & 3;          // staging: row/col r_, 16 k at kq*16
  const int wsw = r_ ^ (kq * 8);                  // swizzled staging column
  float acc[4][4];
  #pragma unroll
  for (int i = 0; i < 4; ++i)
    #pragma unroll
    for (int j = 0; j < 4; ++j) acc[i][j] = 0.f;

  float pa[16], pb[16];
  auto ldA = [&](int kb){
    const float* ap = A + (size_t)(rowb + r_) * lda + kb + kq * 16;
    #pragma unroll
    for (int j = 0; j < 16; ++j) pa[j] = ap[j];
  };
  auto ldB = [&](int kb){
    const float* bp = B + (size_t)(colb + r_) * ldb + kb + kq * 16;
    #pragma unroll
    for (int j = 0; j < 16; ++j) pb[j] = bp[j];
  };
  ldA(0); ldB(0);
  for (int kb = 0; kb < K; kb += 64){
    __syncthreads();
    #pragma unroll
    for (int j = 0; j < 16; ++j){
      As[(kq * 16 + j) * FRS + wsw] = pa[j];
      Bs[(kq * 16 + j) * FRS + wsw] = pb[j];
    }
    __syncthreads();
    if (kb + 64 < K){ ldA(kb + 64); ldB(kb + 64); }
    #pragma unroll 4
    for (int k = 0; k < 64; ++k){
      const int sw = (k >> 4) * 8;
      f32x4 a4 = *(const f32x4*)(As + k * FRS + ((4 * ty) ^ sw));
      f32x4 b4 = *(const f32x4*)(Bs + k * FRS + ((4 * tx) ^ sw));
      acc[0][0] = fmaf(a4[0], b4[0], acc[0][0]); acc[0][1] = fmaf(a4[0], b4[1], acc[0][1]);
      acc[0][2] = fmaf(a4[0], b4[2], acc[0][2]); acc[0][3] = fmaf(a4[0], b4[3], acc[0][3]);
      acc[1][0] = fmaf(a4[1], b4[0], acc[1][0]); acc[1][1] = fmaf(a4[1], b4[1], acc[1][1]);
      acc[1][2] = fmaf(a4[1], b4[2], acc[1][2]); acc[1][3] = fmaf(a4[1], b4[3], acc[1][3]);
      acc[2][0] = fmaf(a4[2], b4[0], acc[2][0]); acc[2][1] = fmaf(a4[2], b4[1], acc[2][1]);
      acc[2][2] = fmaf(a4[2], b4[2], acc[2][2]); acc[2][3] = fmaf(a4[2], b4[3], acc[2][3]);
      acc[3][0] = fmaf(a4[3], b4[0], acc[3][0]); acc[3][1] = fmaf(a4[3], b4[1], acc[3][1]);
      acc[3][2] = fmaf(a4[3], b4[2], acc[3][2]); acc[3][3] = fmaf(a4[3], b4[3], acc[3][3]);
    }
  }
  const int c0 = colb + 4 * tx;
  if (BIAS){
    float bb0 = bih[c0+0] + bhh[c0+0], bb1 = bih[c0+1] + bhh[c0+1];
    float bb2 = bih[c0+2] + bhh[c0+2], bb3 = bih[c0+3] + bhh[c0+3];
    #pragma unroll
    for (int i = 0; i < 4; ++i){
      float* o = outp + (size_t)(rowb + 4 * ty + i) * G4 + c0;
      o[0] = acc[i][0] + bb0; o[1] = acc[i][1] + bb1;
      o[2] = acc[i][2] + bb2; o[3] = acc[i][3] + bb3;
    }
  } else {
    #pragma unroll
    for (int i = 0; i < 4; ++i){
      const size_t base = (size_t)(rowb + 4 * ty + i) * G4 + c0;
      const float* ai = addin + base;
      float* o = outp + base;
      o[0] = acc[i][0] + ai[0]; o[1] = acc[i][1] + ai[1];
      o[2] = acc[i][2] + ai[2]; o[3] = acc[i][3] + ai[3];
    }
  }
}

// ---------------- ts head, j-split (relu-safe): 512 jobs of 8 j-rows ----------------
__device__ void tshead_j(const P& p, int bid, int hbuf){
  const int tid = threadIdx.x;
  const int tm = bid >> 6, tjq = bid & 63;
  const int rowb = tm * 32;
  const int rt = tid >> 3, j8 = tid & 7;
  const int j = tjq * 8 + j8;
  const float* __restrict__ hr = p.h_t + (size_t)hbuf * BB * CF + (size_t)(rowb + rt) * CF;
  const float* __restrict__ wr = p.W_ts1 + (size_t)j * CF;
  float a0=0,a1=0,a2=0,a3=0;
  for (int k = 0; k < CF; k += 16){
    f32x4 h0 = *(const f32x4*)(hr + k),     h1 = *(const f32x4*)(hr + k + 4);
    f32x4 h2 = *(const f32x4*)(hr + k + 8), h3 = *(const f32x4*)(hr + k + 12);
    f32x4 w0 = *(const f32x4*)(wr + k),     w1 = *(const f32x4*)(wr + k + 4);
    f32x4 w2 = *(const f32x4*)(wr + k + 8), w3 = *(const f32x4*)(wr + k + 12);
    a0 = fmaf(h0[0],w0[0], fmaf(h0[1],w0[1], fmaf(h0[2],w0[2], fmaf(h0[3],w0[3], a0))));
    a1 = fmaf(h1[0],w1[0], fmaf(h1[1],w1[1], fmaf(h1[2],w1[2], fmaf(h1[3],w1[3], a1))));
    a2 = fmaf(h2[0],w2[0], fmaf(h2[1],w2[1], fmaf(h2[2],w2[2], fmaf(h2[3],w2[3], a2))));
    a3 = fmaf(h3[0],w3[0], fmaf(h3[1],w3[1], fmaf(h3[2],w3[2], fmaf(h3[3],w3[3], a3))));
  }
  float v = ((a0 + a1) + (a2 + a3)) + p.b_ts1[j];
  v = (v > 0.f ? v : 0.f) * p.W_ts2[j];
  v += __shfl_xor(v, 1, 64);
  v += __shfl_xor(v, 2, 64);
  v += __shfl_xor(v, 4, 64);
  if (j8 == 0) atomicAdd(p.ts_accum + rowb + rt, v);
}

// ---------------- pre kernel. grid 512: half 0 = a (f64 MFMA), half 1 = t (f32 VALU) ----------------
__global__ void __launch_bounds__(NT) k_pre(P p){
  __shared__ __align__(16) char smem[SMEMB];
  const int bid = blockIdx.x;
  const int hsel = bid >> 8, sub = bid & 255;
  const int rowb = (sub >> 6) * 64, colb = (sub & 63) * 64;
  if (hsel == 0)
    mgemm64<true, true, true>(smem, p.t_rec64, TD, p.Wih_a, 768, rowb, colb, TD,
                              nullptr, p.bih_a, p.bhh_a, p.pre_a64);
  else
    dgemm32<true>(smem, p.t_rec32, TD, p.Wih_t, 769, rowb, colb, TD,
                  nullptr, p.bih_t, p.bhh_t, p.pre_t);
}

// ---------------- step A: ts head + recurrent GEMMs. grid 512 ----------------
// a-half on the MFMA pipe, t-half on the VALU pipe; pairs (sub, sub+256) share an XCD/CU
// so the two pipes overlap (m114: time ~ max, not sum).
__global__ void __launch_bounds__(NT) k_stepA(P p, int s){
  __shared__ __align__(16) char smem[SMEMB];
  const int bid = blockIdx.x;
  if (s > 0) tshead_j(p, bid, s & 1);           // ts head for step s-1 (no LDS)
  const int hsel = bid >> 8, sub = bid & 255;
  const int rowb = (sub >> 6) * 64, colb = (sub & 63) * 64;   // colb fast -> XCD-stable
  const int rd = s & 1;
  if (hsel == 0)
    mgemm64<true, true, false>(smem, p.h_a64 + (size_t)rd * BB * CF, CF, p.Whh_a, CF,
                               rowb, colb, CF, p.pre_a64, nullptr, nullptr, p.gacc_a);
  else
    dgemm32<false>(smem, p.h_t + (size_t)rd * BB * CF, CF, p.Whh_t, CF,
                   rowb, colb, CF, p.pre_t, nullptr, nullptr, p.gacc_t);
}

// ---------------- step B: LSTM-a pointwise (f64) + logits/argmax/softmax (f64) + LSTM-t (f32) ----------------
__global__ void __launch_bounds__(NT) k_stepB(P p, int s){
  __shared__ double shd[1092];
  const int b = blockIdx.x, tid = threadIdx.x;
  const int cur = (s + 1) & 1;   // h_a/h_t write buffer
  int idxp = p.idxb[b];
  idxp = idxp < 0 ? 0 : (idxp > 63 ? 63 : idxp);
  {
    const double* ga = p.gacc_a + (size_t)b * G4;       // includes pre_a (biases folded)
    const double* ea = p.E_proj_a64 + (size_t)idxp * G4;
    const int c0 = tid * 4;
    #pragma unroll
    for (int jj = 0; jj < 4; ++jj){
      const int c = c0 + jj;
      double gi = ga[0*CF + c] + ea[0*CF + c];
      double gf = ga[1*CF + c] + ea[1*CF + c];
      double gg = ga[2*CF + c] + ea[2*CF + c];
      double go = ga[3*CF + c] + ea[3*CF + c];
      double cv = p.c_a64[(size_t)b * CF + c];
      double cn = sigd(gf) * cv + sigd(gi) * tanh(gg);
      double hn = sigd(go) * tanh(cn);
      p.c_a64[(size_t)b * CF + c] = cn;
      p.h_a64[(size_t)cur * BB * CF + (size_t)b * CF + c] = hn;
      shd[c] = hn;
    }
  }
  if (tid == 0) shd[1088] = (s == 0) ? 0.0 : ((double)p.ts_accum[b] + (double)p.b_ts2[0]);
  __syncthreads();
  {
    const int w = tid >> 6, l = tid & 63, l15 = l & 15, quad = l >> 4;
    const int a = w * 16 + l15;
    const float* wr = p.W_act + (size_t)a * CF + quad * 256;
    const double* hp = shd + quad * 256;
    double acc = 0.0;
    for (int kk = 0; kk < 256; kk += 4){
      acc = fma((double)wr[kk+0], hp[kk+0], acc);
      acc = fma((double)wr[kk+1], hp[kk+1], acc);
      acc = fma((double)wr[kk+2], hp[kk+2], acc);
      acc = fma((double)wr[kk+3], hp[kk+3], acc);
    }
    acc += __shfl_xor(acc, 16, 64);
    acc += __shfl_xor(acc, 32, 64);
    if (quad == 0) shd[1024 + a] = acc;
  }
  __syncthreads();
  if (tid < 64){
    double acc = shd[1024 + tid] + (double)p.b_act[tid];
    double m = acc;
    #pragma unroll
    for (int off = 32; off; off >>= 1) m = fmax(m, __shfl_xor(m, off, 64));
    unsigned long long ball = __ballot(acc == m);
    int idxv = __ffsll(ball) - 1;               // first max == np.argmax
    idxv = idxv < 0 ? 0 : (idxv > 63 ? 63 : idxv);
    double e = exp(acc - m);
    double ssum = e;
    #pragma unroll
    for (int off = 32; off; off >>= 1) ssum += __shfl_xor(ssum, off, 64);
    p.out[(size_t)b * (NSTEP * NA) + s * NA + tid] = (float)(e / ssum);
    if (tid == 0){
      p.idxb[b] = idxv;
      shd[1089] = (double)idxv;
      if (s > 0) p.out[TS_OFF + b * NSTEP + (s - 1)] = (float)shd[1088];
    }
  }
  __syncthreads();
  const float ts_val = (float)shd[1088];
  const int idxv = (int)shd[1089];
  const int c0 = tid * 4;
  const float* gb = p.gacc_t   + (size_t)b * G4;   // includes pre_t (biases folded)
  const float* eb = p.E_proj_t + (size_t)idxv * G4;
  f32x4 gi = *(const f32x4*)(gb + 0*CF + c0) + *(const f32x4*)(eb + 0*CF + c0) + ts_val * *(const f32x4*)(p.colt + 0*CF + c0);
  f32x4 gf = *(const f32x4*)(gb + 1*CF + c0) + *(const f32x4*)(eb + 1*CF + c0) + ts_val * *(const f32x4*)(p.colt + 1*CF + c0);
  f32x4 gg = *(const f32x4*)(gb + 2*CF + c0) + *(const f32x4*)(eb + 2*CF + c0) + ts_val * *(const f32x4*)(p.colt + 2*CF + c0);
  f32x4 go = *(const f32x4*)(gb + 3*CF + c0) + *(const f32x4*)(eb + 3*CF + c0) + ts_val * *(const f32x4*)(p.colt + 3*CF + c0);
  f32x4 cv = *(f32x4*)(p.c_t + (size_t)b * CF + c0);
  f32x4 cn, hn;
  #pragma unroll
  for (int jj = 0; jj < 4; ++jj){
    float cj = sigf(gf[jj]) * cv[jj] + sigf(gi[jj]) * tanhf_(gg[jj]);
    float hj = sigf(go[jj]) * tanhf_(cj);
    cn[jj] = cj; hn[jj] = hj;
  }
  *(f32x4*)(p.c_t + (size_t)b * CF + c0) = cn;
  *(f32x4*)(p.h_t + (size_t)cur * BB * CF + (size_t)b * CF + c0) = hn;
  __syncthreads();
  if (tid == 0) p.ts_accum[b] = 0.f;   // ready for next step's tshead accumulation
}

// final ts head for step 63 (h_t buffer 0) + write
__global__ void __launch_bounds__(NT) k_tsfin(P p){
  tshead_j(p, blockIdx.x, 0);
}
__global__ void __launch_bounds__(NT) k_tswrite(P p){
  p.out[TS_OFF + threadIdx.x * NSTEP + 63] = p.ts_accum[threadIdx.x] + p.b_ts2[0];
}

extern "C" void kernel_launch(void* const* d_in, const int* in_sizes, int n_in,
                              void* d_out, int out_size, void* d_ws, size_t ws_size,
                              hipStream_t stream){
  (void)in_sizes; (void)n_in; (void)out_size; (void)ws_size;
  P p;
  p.z     = (const float*)d_in[0];  p.W_z2t = (const float*)d_in[1];  p.b_z2t = (const float*)d_in[2];
  p.E     = (const float*)d_in[3];  p.Wih_a = (const float*)d_in[4];  p.Whh_a = (const float*)d_in[5];
  p.bih_a = (const float*)d_in[6];  p.bhh_a = (const float*)d_in[7];  p.Wih_t = (const float*)d_in[8];
  p.Whh_t = (const float*)d_in[9];  p.bih_t = (const float*)d_in[10]; p.bhh_t = (const float*)d_in[11];
  p.W_act = (const float*)d_in[12]; p.b_act = (const float*)d_in[13]; p.W_ts1 = (const float*)d_in[14];
  p.b_ts1 = (const float*)d_in[15]; p.W_ts2 = (const float*)d_in[16]; p.b_ts2 = (const float*)d_in[17];
  p.out = (float*)d_out;
  char* w = (char*)d_ws;
  size_t off = 0;
  auto alloc = [&](size_t bytes) -> void* { void* r = w + off; off += (bytes + 255) & ~(size_t)255; return r; };
  p.t_rec64    = (double*)alloc((size_t)BB * TD * 8);
  p.pre_a64    = (double*)alloc((size_t)BB * G4 * 8);
  p.E_proj_a64 = (double*)alloc((size_t)NA * G4 * 8);
  p.h_a64      = (double*)alloc((size_t)2 * BB * CF * 8);
  p.c_a64      = (double*)alloc((size_t)BB * CF * 8);
  p.gacc_a     = (double*)alloc((size_t)BB * G4 * 8);
  p.t_rec32    = (float*)alloc((size_t)BB * TD * 4);
  p.pre_t      = (float*)alloc((size_t)BB * G4 * 4);
  p.E_proj_t   = (float*)alloc((size_t)NA * G4 * 4);
  p.colt       = (float*)alloc((size_t)G4 * 4);
  p.h_t        = (float*)alloc((size_t)2 * BB * CF * 4);
  p.c_t        = (float*)alloc((size_t)BB * CF * 4);
  p.gacc_t     = (float*)alloc((size_t)BB * G4 * 4);
  p.ts_accum   = (float*)alloc((size_t)BB * 4);
  p.idxb       = (int*)  alloc((size_t)BB * 4);

  k_setup<<<dim3(256), dim3(NT), 0, stream>>>(p);
  k_eproj<<<dim3(528), dim3(NT), 0, stream>>>(p);
  k_pre  <<<dim3(512), dim3(NT), 0, stream>>>(p);
  for (int s = 0; s < NSTEP; ++s){
    k_stepA<<<dim3(512), dim3(NT), 0, stream>>>(p, s);
    k_stepB<<<dim3(256), dim3(NT), 0, stream>>>(p, s);
  }
  k_tsfin  <<<dim3(512), dim3(NT), 0, stream>>>(p);
  k_tswrite<<<dim3(1),   dim3(NT), 0, stream>>>(p);
}